// Round 3
// baseline (800.053 us; speedup 1.0000x reference)
//
#include <hip/hip_runtime.h>

// GATv2 fused: s = a·lrelu(M@W0^T + M[rev]@W1^T + b), segment softmax over dest,
// out = segsum(alpha*M). E=800000, N=50000, D=128.
// R2: bucket-build + per-node register gather (replaced 102.4M fp32-atomic scatter).
// R3: launch_bounds; gather unroll; norm fused into gather.
// R4: pipelined score + fused bucket (REGRESSED +20us: atomics on barrier critical
//     path; sched_barrier pinning). Counters showed the real story: random 512-B row
//     reads of M run at ~1.85 TB/s (line-activate-bound), 2x410 MB of them = ~440us.
// R5: fp16 M copy (Mh). Random bytes halve in BOTH score (M[rev]) and gather (M[e]);
//     score working set (205 MB) now fits L3. fp16 (not bf16): 10-bit mantissa makes
//     the matmul MORE accurate than the old bf16 path, absorbing the Mh quantization
//     in the output sum. Bucket build back to standalone kernel; simple score loop.

#define SLOPE 0.2f
constexpr int E = 800000;
constexpr int N = 50000;
constexpr int D = 128;
constexpr int TILE_E = 64;              // edges per tile
constexpr int NTILES = E / TILE_E;      // 12500 (exact)
constexpr int LDA = 264;                // halves per A row: 256 + 8 pad (bank spread)
constexpr int MAXDEG = 64;              // Poisson(16) max-degree bound; P(overflow) ~1e-13
constexpr int SGRID = 512;              // score grid (2 blocks/CU * 256 CU)

typedef __attribute__((ext_vector_type(8))) _Float16 f16x8;
typedef __attribute__((ext_vector_type(4))) _Float16 f16x4;
typedef __attribute__((ext_vector_type(2))) _Float16 f16x2;
typedef __attribute__((ext_vector_type(4))) float f32x4;

// ---- K0: convert W0,W1 -> Wh[d][k] fp16, k in [0,256): [W0 row d | W1 row d]
__global__ void convert_w(const float* __restrict__ W0, const float* __restrict__ W1,
                          _Float16* __restrict__ Wh) {
    int i = blockIdx.x * blockDim.x + threadIdx.x;   // 0..32767
    if (i >= D * 256) return;
    int d = i >> 8, k = i & 255;
    float v = (k < 128) ? W0[d * 128 + k] : W1[d * 128 + (k - 128)];
    Wh[i] = (_Float16)v;                             // RNE
}

// ---- K_m: M (fp32) -> Mh (fp16). Pure streaming: 410 MB R + 205 MB W.
__global__ __launch_bounds__(256) void convert_m(const float* __restrict__ M,
                                                 _Float16* __restrict__ Mh) {
    const int total = E * D / 4;                     // 25.6M float4 units
    for (int u = blockIdx.x * blockDim.x + threadIdx.x; u < total;
         u += gridDim.x * blockDim.x) {
        float4 v = ((const float4*)M)[u];
        f16x4 h = { (_Float16)v.x, (_Float16)v.y, (_Float16)v.z, (_Float16)v.w };
        ((f16x4*)Mh)[u] = h;
    }
}

// ---- K_b: bucket edges by dest. cnt must be pre-zeroed.
__global__ void bucket_build(const int* __restrict__ dest, int* __restrict__ cnt,
                             int* __restrict__ bucket) {
    int e = blockIdx.x * blockDim.x + threadIdx.x;
    if (e >= E) return;
    int n = dest[e];
    int pos = atomicAdd(&cnt[n], 1);
    if (pos < MAXDEG) bucket[n * MAXDEG + pos] = e;
}

// ---- K1: per edge tile (64e), X[64e][128d] via mfma_f32_16x16x32_f16 over K=256,
// then p[e] = exp(a·lrelu(X+b) + a_b), atomicAdd denom (fire-and-forget).
__global__ __launch_bounds__(512, 4) void score_kernel(
    const _Float16* __restrict__ Mh, const int* __restrict__ dest,
    const int* __restrict__ rev, const _Float16* __restrict__ Wh,
    const float* __restrict__ b0, const float* __restrict__ b1,
    const float* __restrict__ a_w, const float* __restrict__ a_b,
    float* __restrict__ pbuf, float* __restrict__ denom)
{
    __shared__ _Float16 Alds[TILE_E * LDA];   // 33792 B
    __shared__ float red[4][TILE_E];          // 1024 B

    const int t = threadIdx.x;
    const int w = t >> 6;                  // wave 0..7
    const int lane = t & 63;
    const int lo = lane & 15, hi = lane >> 4;
    const int er = (w & 1) * 32;           // edge-quadrant base (32 rows)
    const int dr = (w >> 1) * 32;          // d-quadrant base (32 cols)

    // B fragments resident in registers for the whole kernel: b[j][ks]
    f16x8 b[2][8];
#pragma unroll
    for (int j = 0; j < 2; ++j) {
        int d = dr + j * 16 + lo;
#pragma unroll
        for (int ks = 0; ks < 8; ++ks)
            b[j][ks] = *(const f16x8*)(Wh + d * 256 + ks * 32 + hi * 8);
    }
    float bs[2], aw[2];
#pragma unroll
    for (int j = 0; j < 2; ++j) {
        int d = dr + j * 16 + lo;
        bs[j] = b0[d] + b1[d];
        aw[j] = a_w[d];
    }
    const float ab = a_b[0];

    const int c16 = t & 15;    // 16-B unit within a 128-half row (16 units/row)
    const int r16 = t >> 4;    // 0..31 (rows r16, r16+32)

    for (int tile = blockIdx.x; tile < NTILES; tile += SGRID) {
        const int eb = tile * TILE_E;
        __syncthreads();                       // prior iter done with Alds/red

        // ---- stage A: rows 0..63; halves [0,128)=Mh[e], [128,256)=Mh[rev[e]]
#pragma unroll
        for (int q = 0; q < 2; ++q) {
            int r = r16 + q * 32;
            int rv = rev[eb + r];
            f16x8 hs = ((const f16x8*)(Mh + (size_t)(eb + r) * D))[c16];
            f16x8 hr = ((const f16x8*)(Mh + (size_t)rv * D))[c16];
            *(f16x8*)(Alds + r * LDA + c16 * 8) = hs;
            *(f16x8*)(Alds + r * LDA + 128 + c16 * 8) = hr;
        }
        __syncthreads();

        // ---- MFMA: this wave computes e[er,er+32) x d[dr,dr+32)
        f32x4 zero = {0.f, 0.f, 0.f, 0.f};
        f32x4 acc[2][2];
#pragma unroll
        for (int i = 0; i < 2; ++i)
#pragma unroll
            for (int j = 0; j < 2; ++j) acc[i][j] = zero;

#pragma unroll
        for (int ks = 0; ks < 8; ++ks) {
            f16x8 a[2];
#pragma unroll
            for (int i = 0; i < 2; ++i)
                a[i] = *(const f16x8*)(Alds + (er + i * 16 + lo) * LDA + ks * 32 + hi * 8);
#pragma unroll
            for (int i = 0; i < 2; ++i)
#pragma unroll
                for (int j = 0; j < 2; ++j)
                    acc[i][j] = __builtin_amdgcn_mfma_f32_16x16x32_f16(a[i], b[j][ks], acc[i][j], 0, 0, 0);
        }

        // ---- epilogue: partial s over this wave's 32 d-columns, butterfly over lo
#pragma unroll
        for (int i = 0; i < 2; ++i) {
#pragma unroll
            for (int r = 0; r < 4; ++r) {
                float v = 0.f;
#pragma unroll
                for (int j = 0; j < 2; ++j) {
                    float x = acc[i][j][r] + bs[j];
                    x = (x > 0.f) ? x : SLOPE * x;
                    v += aw[j] * x;
                }
                v += __shfl_xor(v, 1);
                v += __shfl_xor(v, 2);
                v += __shfl_xor(v, 4);
                v += __shfl_xor(v, 8);
                if (lo == 0) red[w >> 1][er + i * 16 + hi * 4 + r] = v;
            }
        }
        __syncthreads();                       // red complete; Alds reads done

        if (t < TILE_E) {
            int e = eb + t;
            float s = red[0][t] + red[1][t] + red[2][t] + red[3][t] + ab;
            float p = __expf(s);               // no max-subtraction needed: |s| = O(1)
            pbuf[e] = p;
            atomicAdd(&denom[dest[e]], p);     // no return use -> fire-and-forget
        }
    }
}

// ---- K3: per-node gather (fp16 rows) with fused normalization. One wave per node.
// Broadcast via readlane; 4 independent 256-B row loads in flight.
__global__ __launch_bounds__(256) void gather_kernel(
    const _Float16* __restrict__ Mh, float* __restrict__ alpha,
    const float* __restrict__ denom,
    const int* __restrict__ cnt, const int* __restrict__ bucket,
    float* __restrict__ out)
{
    const int n = blockIdx.x * 4 + (threadIdx.x >> 6);   // 12500 blocks * 4 waves
    const int lane = threadIdx.x & 63;
    int c = cnt[n];
    c = (c > MAXDEG) ? MAXDEG : c;
    const float dn = denom[n];                 // wave-uniform
    int e = 0; float a = 0.f;
    if (lane < c) {
        e = bucket[n * MAXDEG + lane];
        a = alpha[e] / dn;                     // normalize (same division as ref)
        alpha[e] = a;                          // normalized alpha output (in place)
    }
    float2 acc = {0.f, 0.f};
    int i = 0;
    for (; i + 4 <= c; i += 4) {
        int e0 = __builtin_amdgcn_readlane(e, i + 0);
        int e1 = __builtin_amdgcn_readlane(e, i + 1);
        int e2 = __builtin_amdgcn_readlane(e, i + 2);
        int e3 = __builtin_amdgcn_readlane(e, i + 3);
        float a0 = __uint_as_float(__builtin_amdgcn_readlane(__float_as_uint(a), i + 0));
        float a1 = __uint_as_float(__builtin_amdgcn_readlane(__float_as_uint(a), i + 1));
        float a2 = __uint_as_float(__builtin_amdgcn_readlane(__float_as_uint(a), i + 2));
        float a3 = __uint_as_float(__builtin_amdgcn_readlane(__float_as_uint(a), i + 3));
        f16x2 v0 = ((const f16x2*)(Mh + (size_t)e0 * D))[lane];
        f16x2 v1 = ((const f16x2*)(Mh + (size_t)e1 * D))[lane];
        f16x2 v2 = ((const f16x2*)(Mh + (size_t)e2 * D))[lane];
        f16x2 v3 = ((const f16x2*)(Mh + (size_t)e3 * D))[lane];
        acc.x = fmaf(a0, (float)v0.x, acc.x); acc.y = fmaf(a0, (float)v0.y, acc.y);
        acc.x = fmaf(a1, (float)v1.x, acc.x); acc.y = fmaf(a1, (float)v1.y, acc.y);
        acc.x = fmaf(a2, (float)v2.x, acc.x); acc.y = fmaf(a2, (float)v2.y, acc.y);
        acc.x = fmaf(a3, (float)v3.x, acc.x); acc.y = fmaf(a3, (float)v3.y, acc.y);
    }
    for (; i < c; ++i) {
        int   ei = __builtin_amdgcn_readlane(e, i);
        float ai = __uint_as_float(__builtin_amdgcn_readlane(__float_as_uint(a), i));
        f16x2 v = ((const f16x2*)(Mh + (size_t)ei * D))[lane];
        acc.x = fmaf(ai, (float)v.x, acc.x);
        acc.y = fmaf(ai, (float)v.y, acc.y);
    }
    ((float2*)(out + (size_t)n * D))[lane] = acc;
}

extern "C" void kernel_launch(void* const* d_in, const int* in_sizes, int n_in,
                              void* d_out, int out_size, void* d_ws, size_t ws_size,
                              hipStream_t stream) {
    const float* M   = (const float*)d_in[0];
    const int*   dst = (const int*)d_in[1];
    const int*   rev = (const int*)d_in[2];
    // d_in[3] = dim_size (compile-time constant N)
    const float* W0  = (const float*)d_in[4];
    const float* b0  = (const float*)d_in[5];
    const float* W1  = (const float*)d_in[6];
    const float* b1  = (const float*)d_in[7];
    const float* a_w = (const float*)d_in[8];
    const float* a_b = (const float*)d_in[9];

    float* out   = (float*)d_out;            // [N,128]
    float* alpha = out + (size_t)N * D;      // [E]  (holds p, then normalized alpha)

    float*     denom  = (float*)d_ws;                    // [N] fp32        (200000 B)
    int*       cnt    = (int*)(denom + N);               // [N]             (200000 B)
    _Float16*  Wh     = (_Float16*)(cnt + N);            // [128][256] fp16 (65536 B)
    _Float16*  Mh     = Wh + D * 256;                    // [E][128] fp16   (204.8 MB)
    int*       bucket = (int*)(Mh + (size_t)E * D);      // [N][MAXDEG]     (12.8 MB)

    hipMemsetAsync(denom, 0, (size_t)2 * N * sizeof(float), stream);  // denom + cnt

    convert_w<<<128, 256, 0, stream>>>(W0, W1, Wh);
    convert_m<<<4096, 256, 0, stream>>>(M, Mh);
    bucket_build<<<(E + 255) / 256, 256, 0, stream>>>(dst, cnt, bucket);
    score_kernel<<<SGRID, 512, 0, stream>>>(Mh, dst, rev, Wh, b0, b1, a_w, a_b,
                                            alpha, denom);
    gather_kernel<<<N / 4, 256, 0, stream>>>(Mh, alpha, denom, cnt, bucket, out);
}